// Round 1
// baseline (162.895 us; speedup 1.0000x reference)
//
#include <hip/hip_runtime.h>
#include <hip/hip_fp16.h>

#define DD 64
#define NPB 64          // nodes per block (node kernel)
#define LP 72           // padded LDS row stride in halves (144 B): 2-way-only bank aliasing
#define MAXB 512        // max src-buckets for binning

typedef _Float16 f16x8 __attribute__((ext_vector_type(8)));
typedef float    f32x4 __attribute__((ext_vector_type(4)));

// Node-level transform on MFMA f16 (fp32 accumulate):
//   A = (K_h + P_e) @ W1 + b1   (stored fp16)
//   B = Q_h @ W1                (stored fp16)
// 64 nodes/block, 4 waves; wave w computes rows w*16..w*16+15 of BOTH outputs
// via 16x16x32 MFMA. Block 0 additionally zeroes the bucket counters for the
// edge-binning pass (stream order guarantees this precedes hist_kernel).
__global__ __launch_bounds__(256) void node_transform_mfma(
    const float* __restrict__ K_h, const float* __restrict__ Q_h,
    const float* __restrict__ P_e, const float* __restrict__ W1,
    const float* __restrict__ b1, __half* __restrict__ A,
    __half* __restrict__ Bm, int n_nodes, int* __restrict__ counts)
{
    __shared__ __half XH [NPB][LP];   // fp16(K+P)
    __shared__ __half QH [NPB][LP];   // fp16(Q)
    __shared__ __half W1T[DD][LP];    // W1 transposed: W1T[n][k] = W1[k][n]

    const int tid   = threadIdx.x;
    const int nbase = blockIdx.x * NPB;

    if (blockIdx.x == 0) {
        for (int i = tid; i < MAXB; i += 256) counts[i] = 0;
    }

    // ---- Stage W1T (8 KB): thread t reads W1[k][n0..n0+15], scatters column-wise ----
    {
        const int k  = tid >> 2;
        const int n0 = (tid & 3) << 4;
        const float* wr = W1 + k * DD + n0;
        float4 w0 = *(const float4*)(wr);
        float4 w1v = *(const float4*)(wr + 4);
        float4 w2v = *(const float4*)(wr + 8);
        float4 w3v = *(const float4*)(wr + 12);
        const float wv[16] = {w0.x,w0.y,w0.z,w0.w, w1v.x,w1v.y,w1v.z,w1v.w,
                              w2v.x,w2v.y,w2v.z,w2v.w, w3v.x,w3v.y,w3v.z,w3v.w};
#pragma unroll
        for (int j = 0; j < 16; ++j)
            W1T[n0 + j][k] = __float2half(wv[j]);
    }

    // ---- Stage XH = fp16(K+P), QH = fp16(Q); coalesced float4 global reads ----
#pragma unroll
    for (int ch = 0; ch < 4; ++ch) {
        int idx = tid + (ch << 8);        // float4 index over [64 rows][16]
        int r   = idx >> 4;
        int q4  = idx & 15;
        int node = nbase + r;
        float4 kv = make_float4(0.f,0.f,0.f,0.f);
        float4 pv = kv, qv = kv;
        if (node < n_nodes) {
            kv = *(const float4*)(K_h + (size_t)node * DD + q4 * 4);
            pv = *(const float4*)(P_e + (size_t)node * DD + q4 * 4);
            qv = *(const float4*)(Q_h + (size_t)node * DD + q4 * 4);
        }
        __half2* xh = (__half2*)&XH[r][q4 << 2];
        xh[0] = __float22half2_rn(make_float2(kv.x + pv.x, kv.y + pv.y));
        xh[1] = __float22half2_rn(make_float2(kv.z + pv.z, kv.w + pv.w));
        __half2* qh = (__half2*)&QH[r][q4 << 2];
        qh[0] = __float22half2_rn(make_float2(qv.x, qv.y));
        qh[1] = __float22half2_rn(make_float2(qv.z, qv.w));
    }
    __syncthreads();

    // ---- MFMA main: wave w, lane (m = lane&15, q = lane>>4) ----
    const int w    = tid >> 6;
    const int lane = tid & 63;
    const int m    = lane & 15;
    const int q    = lane >> 4;
    const int row  = (w << 4) + m;

    f16x8 xlo = *(const f16x8*)&XH[row][(q << 3)];
    f16x8 xhi = *(const f16x8*)&XH[row][32 + (q << 3)];
    f16x8 qlo = *(const f16x8*)&QH[row][(q << 3)];
    f16x8 qhi = *(const f16x8*)&QH[row][32 + (q << 3)];

    f32x4 accA[4], accB[4];
#pragma unroll
    for (int t = 0; t < 4; ++t) {
        float bb = b1[t * 16 + m];            // b1 folded into A accumulator
        accA[t] = (f32x4){bb, bb, bb, bb};
        accB[t] = (f32x4){0.f, 0.f, 0.f, 0.f};
        f16x8 wlo = *(const f16x8*)&W1T[t * 16 + m][(q << 3)];
        f16x8 whi = *(const f16x8*)&W1T[t * 16 + m][32 + (q << 3)];
        accA[t] = __builtin_amdgcn_mfma_f32_16x16x32_f16(xlo, wlo, accA[t], 0, 0, 0);
        accA[t] = __builtin_amdgcn_mfma_f32_16x16x32_f16(xhi, whi, accA[t], 0, 0, 0);
        accB[t] = __builtin_amdgcn_mfma_f32_16x16x32_f16(qlo, wlo, accB[t], 0, 0, 0);
        accB[t] = __builtin_amdgcn_mfma_f32_16x16x32_f16(qhi, whi, accB[t], 0, 0, 0);
    }

    // ---- Store: acc[t][r] -> out[nbase + w*16 + q*4 + r][t*16 + m] ----
#pragma unroll
    for (int r = 0; r < 4; ++r) {
        int node = nbase + (w << 4) + (q << 2) + r;
        if (node >= n_nodes) continue;
        __half* Arow = A  + (size_t)node * DD + m;
        __half* Brow = Bm + (size_t)node * DD + m;
#pragma unroll
        for (int t = 0; t < 4; ++t) {
            Arow[t * 16] = __float2half(accA[t][r]);
            Brow[t * 16] = __float2half(accB[t][r]);
        }
    }
}

// ---- Edge binning: counting sort of edges by src bucket (src >> shift). ----
// Makes the A-row gather in the edge kernel L2/L1-local (16 KB slice per
// bucket at shift=7) instead of random over the 6.4 MB A array.

__global__ __launch_bounds__(256) void hist_kernel(
    const int* __restrict__ src, int* __restrict__ counts,
    int n_edges, int shift)
{
    __shared__ int lh[MAXB];
    for (int i = threadIdx.x; i < MAXB; i += 256) lh[i] = 0;
    __syncthreads();
    int idx    = blockIdx.x * blockDim.x + threadIdx.x;
    int stride = gridDim.x * blockDim.x;
    for (int e = idx; e < n_edges; e += stride)
        atomicAdd(&lh[src[e] >> shift], 1);
    __syncthreads();
    for (int i = threadIdx.x; i < MAXB; i += 256)
        if (lh[i]) atomicAdd(&counts[i], lh[i]);
}

// Exclusive scan of counts -> cursors. nb <= MAXB, single block of MAXB threads.
__global__ __launch_bounds__(MAXB) void scan_kernel(
    const int* __restrict__ counts, int* __restrict__ cursors, int nb)
{
    __shared__ int buf[2][MAXB];
    const int t = threadIdx.x;
    int v = (t < nb) ? counts[t] : 0;
    buf[0][t] = v;
    __syncthreads();
    int s = 0;
#pragma unroll
    for (int off = 1; off < MAXB; off <<= 1) {
        int x = buf[s][t];
        if (t >= off) x += buf[s][t - off];
        buf[s ^ 1][t] = x;
        s ^= 1;
        __syncthreads();
    }
    if (t < nb) cursors[t] = buf[s][t] - v;   // exclusive
}

// Scatter edges into bucket order. Each block owns a contiguous edge chunk:
// local histogram -> one global atomicAdd per touched bucket (range reserve)
// -> second pass writes (src,dst) pairs + original edge id at unique slots.
__global__ __launch_bounds__(256) void scatter_kernel(
    const int* __restrict__ src, const int* __restrict__ dst,
    int* __restrict__ cursors, int2* __restrict__ sd, int* __restrict__ eid,
    int n_edges, int shift)
{
    __shared__ int lh[MAXB];
    __shared__ int base[MAXB];
    const int t     = threadIdx.x;
    const int chunk = (n_edges + gridDim.x - 1) / gridDim.x;
    const int e0    = blockIdx.x * chunk;
    const int e1    = (e0 + chunk < n_edges) ? e0 + chunk : n_edges;

    for (int i = t; i < MAXB; i += 256) lh[i] = 0;
    __syncthreads();
    for (int e = e0 + t; e < e1; e += 256)
        atomicAdd(&lh[src[e] >> shift], 1);
    __syncthreads();
    for (int i = t; i < MAXB; i += 256) {
        int c = lh[i];
        base[i] = c ? atomicAdd(&cursors[i], c) : 0;
        lh[i] = 0;
    }
    __syncthreads();
    for (int e = e0 + t; e < e1; e += 256) {
        int sv = src[e];
        int b  = sv >> shift;
        int pos = base[b] + atomicAdd(&lh[b], 1);
        sd[pos]  = make_int2(sv, dst[e]);
        eid[pos] = e;
    }
}

// Edge-level: score[e] = relu(A[src[e]] - B[dst[e]]) . W2 + b2
// 8 lanes per edge, 4 edges per lane-group. Consumes binned (src,dst,eid):
// A-gathers are bucket-local (L2/L1 hits); result scattered to out[eid].
__global__ __launch_bounds__(256) void edge_score_binned(
    const __half* __restrict__ A, const __half* __restrict__ Bm,
    const int2* __restrict__ sd, const int* __restrict__ eid,
    const float* __restrict__ W2, const float* __restrict__ b2,
    float* __restrict__ out, int n_edges)
{
    const int tid = threadIdx.x;
    const int g   = tid >> 3;                   // lane-group 0..31
    const int c   = tid & 7;                    // 16B chunk within row
    const int e0  = (blockIdx.x << 7) + (g << 2);  // 128 edges per block
    if (e0 >= n_edges) return;

    float4 w0 = *(const float4*)(W2 + c * 8);   // uniform -> s_load
    float4 w1 = *(const float4*)(W2 + c * 8 + 4);
    const float wv[8] = {w0.x, w0.y, w0.z, w0.w, w1.x, w1.y, w1.z, w1.w};
    const size_t coff = (size_t)(c * 8);

    if (e0 + 3 < n_edges) {
        int4 p01 = *(const int4*)(sd + e0);       // s0,d0,s1,d1 (16B aligned: e0%4==0)
        int4 p23 = *(const int4*)(sd + e0 + 2);   // s2,d2,s3,d3
        int4 ev  = *(const int4*)(eid + e0);

        // Issue all 8 row loads back-to-back.
        float4 ra0 = *(const float4*)(A  + (size_t)p01.x * DD + coff);
        float4 rb0 = *(const float4*)(Bm + (size_t)p01.y * DD + coff);
        float4 ra1 = *(const float4*)(A  + (size_t)p01.z * DD + coff);
        float4 rb1 = *(const float4*)(Bm + (size_t)p01.w * DD + coff);
        float4 ra2 = *(const float4*)(A  + (size_t)p23.x * DD + coff);
        float4 rb2 = *(const float4*)(Bm + (size_t)p23.y * DD + coff);
        float4 ra3 = *(const float4*)(A  + (size_t)p23.z * DD + coff);
        float4 rb3 = *(const float4*)(Bm + (size_t)p23.w * DD + coff);

        float acc0 = 0.f, acc1 = 0.f, acc2 = 0.f, acc3 = 0.f;
        const __half2* ah0 = (const __half2*)&ra0;
        const __half2* bh0 = (const __half2*)&rb0;
        const __half2* ah1 = (const __half2*)&ra1;
        const __half2* bh1 = (const __half2*)&rb1;
        const __half2* ah2 = (const __half2*)&ra2;
        const __half2* bh2 = (const __half2*)&rb2;
        const __half2* ah3 = (const __half2*)&ra3;
        const __half2* bh3 = (const __half2*)&rb3;
#pragma unroll
        for (int j = 0; j < 4; ++j) {
            float2 x, y;
            x = __half22float2(ah0[j]); y = __half22float2(bh0[j]);
            acc0 = fmaf(fmaxf(x.x - y.x, 0.f), wv[2 * j + 0], acc0);
            acc0 = fmaf(fmaxf(x.y - y.y, 0.f), wv[2 * j + 1], acc0);
            x = __half22float2(ah1[j]); y = __half22float2(bh1[j]);
            acc1 = fmaf(fmaxf(x.x - y.x, 0.f), wv[2 * j + 0], acc1);
            acc1 = fmaf(fmaxf(x.y - y.y, 0.f), wv[2 * j + 1], acc1);
            x = __half22float2(ah2[j]); y = __half22float2(bh2[j]);
            acc2 = fmaf(fmaxf(x.x - y.x, 0.f), wv[2 * j + 0], acc2);
            acc2 = fmaf(fmaxf(x.y - y.y, 0.f), wv[2 * j + 1], acc2);
            x = __half22float2(ah3[j]); y = __half22float2(bh3[j]);
            acc3 = fmaf(fmaxf(x.x - y.x, 0.f), wv[2 * j + 0], acc3);
            acc3 = fmaf(fmaxf(x.y - y.y, 0.f), wv[2 * j + 1], acc3);
        }

        acc0 += __shfl_xor(acc0, 1); acc1 += __shfl_xor(acc1, 1);
        acc2 += __shfl_xor(acc2, 1); acc3 += __shfl_xor(acc3, 1);
        acc0 += __shfl_xor(acc0, 2); acc1 += __shfl_xor(acc1, 2);
        acc2 += __shfl_xor(acc2, 2); acc3 += __shfl_xor(acc3, 2);
        acc0 += __shfl_xor(acc0, 4); acc1 += __shfl_xor(acc1, 4);
        acc2 += __shfl_xor(acc2, 4); acc3 += __shfl_xor(acc3, 4);

        if (c == 0) {
            float bb = b2[0];
            out[ev.x] = acc0 + bb;
            out[ev.y] = acc1 + bb;
            out[ev.z] = acc2 + bb;
            out[ev.w] = acc3 + bb;
        }
    } else {
        for (int e = e0; e < n_edges && e < e0 + 4; ++e) {
            int2 p = sd[e];
            float4 ar = *(const float4*)(A  + (size_t)p.x * DD + coff);
            float4 br = *(const float4*)(Bm + (size_t)p.y * DD + coff);
            const __half2* ah = (const __half2*)&ar;
            const __half2* bh = (const __half2*)&br;
            float acc = 0.f;
#pragma unroll
            for (int j = 0; j < 4; ++j) {
                float2 x = __half22float2(ah[j]);
                float2 y = __half22float2(bh[j]);
                acc = fmaf(fmaxf(x.x - y.x, 0.f), wv[2 * j + 0], acc);
                acc = fmaf(fmaxf(x.y - y.y, 0.f), wv[2 * j + 1], acc);
            }
            acc += __shfl_xor(acc, 1);
            acc += __shfl_xor(acc, 2);
            acc += __shfl_xor(acc, 4);
            if (c == 0) out[eid[e]] = acc + b2[0];
        }
    }
}

extern "C" void kernel_launch(void* const* d_in, const int* in_sizes, int n_in,
                              void* d_out, int out_size, void* d_ws, size_t ws_size,
                              hipStream_t stream) {
    const float* K_h = (const float*)d_in[0];
    const float* Q_h = (const float*)d_in[1];
    const float* P_e = (const float*)d_in[2];
    const int*   src = (const int*)d_in[3];
    const int*   dst = (const int*)d_in[4];
    const float* W1  = (const float*)d_in[5];
    const float* b1  = (const float*)d_in[6];
    const float* W2  = (const float*)d_in[7];
    const float* b2  = (const float*)d_in[8];
    float* out = (float*)d_out;

    int n_nodes = in_sizes[0] / DD;
    int n_edges = in_sizes[3];

    // Bucket shift: 128-node buckets (16 KB A-slice) unless that would
    // exceed MAXB buckets.
    int shift = 7;
    while ((((n_nodes - 1) >> shift) + 1) > MAXB) ++shift;
    int nb = ((n_nodes - 1) >> shift) + 1;

    // Workspace layout (all sizes 256B-aligned):
    //   A  [n][64] fp16, B [n][64] fp16   (12.8 MB)
    //   sd [E] int2 (binned src,dst)      ( 6.4 MB)
    //   eid[E] int  (original edge id)    ( 3.2 MB)
    //   counts[MAXB], cursors[MAXB]
    size_t nA = (size_t)n_nodes * DD;
    __half* A  = (__half*)d_ws;
    __half* Bm = A + nA;
    char* p = (char*)(Bm + nA);
    p = (char*)(((size_t)p + 255) & ~(size_t)255);
    int2* sd = (int2*)p;   p += (size_t)n_edges * sizeof(int2);
    p = (char*)(((size_t)p + 255) & ~(size_t)255);
    int* eid = (int*)p;    p += (size_t)n_edges * sizeof(int);
    p = (char*)(((size_t)p + 255) & ~(size_t)255);
    int* counts  = (int*)p;  p += MAXB * sizeof(int);
    int* cursors = (int*)p;

    node_transform_mfma<<<(n_nodes + NPB - 1) / NPB, 256, 0, stream>>>(
        K_h, Q_h, P_e, W1, b1, A, Bm, n_nodes, counts);
    hist_kernel<<<256, 256, 0, stream>>>(src, counts, n_edges, shift);
    scan_kernel<<<1, MAXB, 0, stream>>>(counts, cursors, nb);
    scatter_kernel<<<256, 256, 0, stream>>>(src, dst, cursors, sd, eid,
                                            n_edges, shift);
    edge_score_binned<<<(n_edges + 127) / 128, 256, 0, stream>>>(
        A, Bm, sd, eid, W2, b2, out, n_edges);
}

// Round 2
// 134.590 us; speedup vs baseline: 1.2103x; 1.2103x over previous
//
#include <hip/hip_runtime.h>
#include <hip/hip_fp16.h>

#define DD 64
#define NPB 64          // nodes per block (node kernel)
#define LP 72           // padded LDS row stride in halves (144 B): 2-way-only bank aliasing
#define NB 8            // dst-buckets == XCDs

typedef _Float16 f16x8 __attribute__((ext_vector_type(8)));
typedef float    f32x4 __attribute__((ext_vector_type(4)));

// Node-level transform on MFMA f16 (fp32 accumulate):
//   A = (K_h + P_e) @ W1 + b1   (stored fp16)
//   B = Q_h @ W1                (stored fp16)
// 64 nodes/block, 4 waves. Block 0 additionally zeroes the NB bucket counters
// (stream order guarantees this precedes bin_edges).
__global__ __launch_bounds__(256) void node_transform_mfma(
    const float* __restrict__ K_h, const float* __restrict__ Q_h,
    const float* __restrict__ P_e, const float* __restrict__ W1,
    const float* __restrict__ b1, __half* __restrict__ A,
    __half* __restrict__ Bm, int n_nodes, int* __restrict__ counts)
{
    __shared__ __half XH [NPB][LP];   // fp16(K+P)
    __shared__ __half QH [NPB][LP];   // fp16(Q)
    __shared__ __half W1T[DD][LP];    // W1 transposed: W1T[n][k] = W1[k][n]

    const int tid   = threadIdx.x;
    const int nbase = blockIdx.x * NPB;

    if (blockIdx.x == 0 && tid < NB) counts[tid] = 0;

    // ---- Stage W1T (8 KB): thread t reads W1[k][n0..n0+15], scatters column-wise ----
    {
        const int k  = tid >> 2;
        const int n0 = (tid & 3) << 4;
        const float* wr = W1 + k * DD + n0;
        float4 w0 = *(const float4*)(wr);
        float4 w1v = *(const float4*)(wr + 4);
        float4 w2v = *(const float4*)(wr + 8);
        float4 w3v = *(const float4*)(wr + 12);
        const float wv[16] = {w0.x,w0.y,w0.z,w0.w, w1v.x,w1v.y,w1v.z,w1v.w,
                              w2v.x,w2v.y,w2v.z,w2v.w, w3v.x,w3v.y,w3v.z,w3v.w};
#pragma unroll
        for (int j = 0; j < 16; ++j)
            W1T[n0 + j][k] = __float2half(wv[j]);
    }

    // ---- Stage XH = fp16(K+P), QH = fp16(Q); coalesced float4 global reads ----
#pragma unroll
    for (int ch = 0; ch < 4; ++ch) {
        int idx = tid + (ch << 8);        // float4 index over [64 rows][16]
        int r   = idx >> 4;
        int q4  = idx & 15;
        int node = nbase + r;
        float4 kv = make_float4(0.f,0.f,0.f,0.f);
        float4 pv = kv, qv = kv;
        if (node < n_nodes) {
            kv = *(const float4*)(K_h + (size_t)node * DD + q4 * 4);
            pv = *(const float4*)(P_e + (size_t)node * DD + q4 * 4);
            qv = *(const float4*)(Q_h + (size_t)node * DD + q4 * 4);
        }
        __half2* xh = (__half2*)&XH[r][q4 << 2];
        xh[0] = __float22half2_rn(make_float2(kv.x + pv.x, kv.y + pv.y));
        xh[1] = __float22half2_rn(make_float2(kv.z + pv.z, kv.w + pv.w));
        __half2* qh = (__half2*)&QH[r][q4 << 2];
        qh[0] = __float22half2_rn(make_float2(qv.x, qv.y));
        qh[1] = __float22half2_rn(make_float2(qv.z, qv.w));
    }
    __syncthreads();

    // ---- MFMA main: wave w, lane (m = lane&15, q = lane>>4) ----
    const int w    = tid >> 6;
    const int lane = tid & 63;
    const int m    = lane & 15;
    const int q    = lane >> 4;
    const int row  = (w << 4) + m;

    f16x8 xlo = *(const f16x8*)&XH[row][(q << 3)];
    f16x8 xhi = *(const f16x8*)&XH[row][32 + (q << 3)];
    f16x8 qlo = *(const f16x8*)&QH[row][(q << 3)];
    f16x8 qhi = *(const f16x8*)&QH[row][32 + (q << 3)];

    f32x4 accA[4], accB[4];
#pragma unroll
    for (int t = 0; t < 4; ++t) {
        float bb = b1[t * 16 + m];            // b1 folded into A accumulator
        accA[t] = (f32x4){bb, bb, bb, bb};
        accB[t] = (f32x4){0.f, 0.f, 0.f, 0.f};
        f16x8 wlo = *(const f16x8*)&W1T[t * 16 + m][(q << 3)];
        f16x8 whi = *(const f16x8*)&W1T[t * 16 + m][32 + (q << 3)];
        accA[t] = __builtin_amdgcn_mfma_f32_16x16x32_f16(xlo, wlo, accA[t], 0, 0, 0);
        accA[t] = __builtin_amdgcn_mfma_f32_16x16x32_f16(xhi, whi, accA[t], 0, 0, 0);
        accB[t] = __builtin_amdgcn_mfma_f32_16x16x32_f16(qlo, wlo, accB[t], 0, 0, 0);
        accB[t] = __builtin_amdgcn_mfma_f32_16x16x32_f16(qhi, whi, accB[t], 0, 0, 0);
    }

    // ---- Store: acc[t][r] -> out[nbase + w*16 + q*4 + r][t*16 + m] ----
#pragma unroll
    for (int r = 0; r < 4; ++r) {
        int node = nbase + (w << 4) + (q << 2) + r;
        if (node >= n_nodes) continue;
        __half* Arow = A  + (size_t)node * DD + m;
        __half* Brow = Bm + (size_t)node * DD + m;
#pragma unroll
        for (int t = 0; t < 4; ++t) {
            Arow[t * 16] = __float2half(accA[t][r]);
            Brow[t * 16] = __float2half(accB[t][r]);
        }
    }
}

// ---- 8-bucket dst binning (single kernel, fixed-capacity buckets). ----
// Bucket g = dst / bdiv (bdiv = ceil(n_nodes/NB)); bucket g's slots live at
// [g*cap, g*cap+cap). Per block: LDS histogram -> NB global atomicAdds to
// reserve contiguous ranges -> scatter (src,dst) + edge id. Overflow edges
// (bucket count > cap; impossible for near-uniform dst, but kept for
// correctness) are scored inline here.
__global__ __launch_bounds__(256) void bin_edges(
    const int* __restrict__ src, const int* __restrict__ dst,
    int* __restrict__ counts, int2* __restrict__ sd, int* __restrict__ eid,
    int n_edges, int bdiv, int cap,
    const __half* __restrict__ A, const __half* __restrict__ Bm,
    const float* __restrict__ W2, const float* __restrict__ b2,
    float* __restrict__ out)
{
    __shared__ int lh[NB], lbase[NB], lcur[NB];
    const int t     = threadIdx.x;
    const int chunk = (n_edges + gridDim.x - 1) / gridDim.x;
    const int e0    = blockIdx.x * chunk;
    const int e1    = (e0 + chunk < n_edges) ? e0 + chunk : n_edges;

    if (t < NB) lh[t] = 0;
    __syncthreads();
    for (int e = e0 + t; e < e1; e += 256)
        atomicAdd(&lh[dst[e] / bdiv], 1);
    __syncthreads();
    if (t < NB) {
        int c = lh[t];
        lbase[t] = c ? atomicAdd(&counts[t], c) : 0;
        lcur[t]  = 0;
    }
    __syncthreads();
    for (int e = e0 + t; e < e1; e += 256) {
        int d = dst[e];
        int g = d / bdiv;
        int sv = src[e];
        int posl = lbase[g] + atomicAdd(&lcur[g], 1);
        if (posl < cap) {
            int pos = g * cap + posl;
            sd[pos]  = make_int2(sv, d);
            eid[pos] = e;
        } else {
            // cold fallback: score this edge directly
            const __half2* ar = (const __half2*)(A  + (size_t)sv * DD);
            const __half2* br = (const __half2*)(Bm + (size_t)d  * DD);
            float acc = b2[0];
            for (int j = 0; j < 32; ++j) {
                float2 x = __half22float2(ar[j]);
                float2 y = __half22float2(br[j]);
                acc = fmaf(fmaxf(x.x - y.x, 0.f), W2[2 * j + 0], acc);
                acc = fmaf(fmaxf(x.y - y.y, 0.f), W2[2 * j + 1], acc);
            }
            out[e] = acc;
        }
    }
}

// Edge-level: score[e] = relu(A[src[e]] - B[dst[e]]) . W2 + b2
// 8 lanes per edge, 4 edges per lane-group, 128 edges per block.
// Bucket = blockIdx % 8 == XCD (round-robin dispatch): each XCD keeps its
// ~800 KB B-slice L2-resident; A-side stays random (~50% hit in leftover L2).
__global__ __launch_bounds__(256) void edge_score_binned(
    const __half* __restrict__ A, const __half* __restrict__ Bm,
    const int2* __restrict__ sd, const int* __restrict__ eid,
    const int* __restrict__ counts, const float* __restrict__ W2,
    const float* __restrict__ b2, float* __restrict__ out, int cap)
{
    const int gb  = blockIdx.x & (NB - 1);     // bucket == XCD pin
    const int sb  = blockIdx.x >> 3;
    int cnt = counts[gb];
    if (cnt > cap) cnt = cap;                  // overflow handled in bin_edges
    const int tid = threadIdx.x;
    const int g   = tid >> 3;                  // lane-group 0..31
    const int c   = tid & 7;                   // 16B chunk within row
    const int l0  = (sb << 7) + (g << 2);      // local edge idx in bucket
    if (l0 >= cnt) return;
    const int e0  = gb * cap + l0;             // cap%4==0 -> e0%4==0 (aligned)

    float4 w0 = *(const float4*)(W2 + c * 8);  // uniform -> s_load
    float4 w1 = *(const float4*)(W2 + c * 8 + 4);
    const float wv[8] = {w0.x, w0.y, w0.z, w0.w, w1.x, w1.y, w1.z, w1.w};
    const size_t coff = (size_t)(c * 8);

    if (l0 + 3 < cnt) {
        int4 p01 = *(const int4*)(sd + e0);       // s0,d0,s1,d1
        int4 p23 = *(const int4*)(sd + e0 + 2);   // s2,d2,s3,d3
        int4 ev  = *(const int4*)(eid + e0);

        // Issue all 8 row loads back-to-back.
        float4 ra0 = *(const float4*)(A  + (size_t)p01.x * DD + coff);
        float4 rb0 = *(const float4*)(Bm + (size_t)p01.y * DD + coff);
        float4 ra1 = *(const float4*)(A  + (size_t)p01.z * DD + coff);
        float4 rb1 = *(const float4*)(Bm + (size_t)p01.w * DD + coff);
        float4 ra2 = *(const float4*)(A  + (size_t)p23.x * DD + coff);
        float4 rb2 = *(const float4*)(Bm + (size_t)p23.y * DD + coff);
        float4 ra3 = *(const float4*)(A  + (size_t)p23.z * DD + coff);
        float4 rb3 = *(const float4*)(Bm + (size_t)p23.w * DD + coff);

        float acc0 = 0.f, acc1 = 0.f, acc2 = 0.f, acc3 = 0.f;
        const __half2* ah0 = (const __half2*)&ra0;
        const __half2* bh0 = (const __half2*)&rb0;
        const __half2* ah1 = (const __half2*)&ra1;
        const __half2* bh1 = (const __half2*)&rb1;
        const __half2* ah2 = (const __half2*)&ra2;
        const __half2* bh2 = (const __half2*)&rb2;
        const __half2* ah3 = (const __half2*)&ra3;
        const __half2* bh3 = (const __half2*)&rb3;
#pragma unroll
        for (int j = 0; j < 4; ++j) {
            float2 x, y;
            x = __half22float2(ah0[j]); y = __half22float2(bh0[j]);
            acc0 = fmaf(fmaxf(x.x - y.x, 0.f), wv[2 * j + 0], acc0);
            acc0 = fmaf(fmaxf(x.y - y.y, 0.f), wv[2 * j + 1], acc0);
            x = __half22float2(ah1[j]); y = __half22float2(bh1[j]);
            acc1 = fmaf(fmaxf(x.x - y.x, 0.f), wv[2 * j + 0], acc1);
            acc1 = fmaf(fmaxf(x.y - y.y, 0.f), wv[2 * j + 1], acc1);
            x = __half22float2(ah2[j]); y = __half22float2(bh2[j]);
            acc2 = fmaf(fmaxf(x.x - y.x, 0.f), wv[2 * j + 0], acc2);
            acc2 = fmaf(fmaxf(x.y - y.y, 0.f), wv[2 * j + 1], acc2);
            x = __half22float2(ah3[j]); y = __half22float2(bh3[j]);
            acc3 = fmaf(fmaxf(x.x - y.x, 0.f), wv[2 * j + 0], acc3);
            acc3 = fmaf(fmaxf(x.y - y.y, 0.f), wv[2 * j + 1], acc3);
        }

        acc0 += __shfl_xor(acc0, 1); acc1 += __shfl_xor(acc1, 1);
        acc2 += __shfl_xor(acc2, 1); acc3 += __shfl_xor(acc3, 1);
        acc0 += __shfl_xor(acc0, 2); acc1 += __shfl_xor(acc1, 2);
        acc2 += __shfl_xor(acc2, 2); acc3 += __shfl_xor(acc3, 2);
        acc0 += __shfl_xor(acc0, 4); acc1 += __shfl_xor(acc1, 4);
        acc2 += __shfl_xor(acc2, 4); acc3 += __shfl_xor(acc3, 4);

        if (c == 0) {
            float bb = b2[0];
            out[ev.x] = acc0 + bb;
            out[ev.y] = acc1 + bb;
            out[ev.z] = acc2 + bb;
            out[ev.w] = acc3 + bb;
        }
    } else {
        for (int l = l0; l < cnt && l < l0 + 4; ++l) {
            int e = gb * cap + l;
            int2 p = sd[e];
            float4 ar = *(const float4*)(A  + (size_t)p.x * DD + coff);
            float4 br = *(const float4*)(Bm + (size_t)p.y * DD + coff);
            const __half2* ah = (const __half2*)&ar;
            const __half2* bh = (const __half2*)&br;
            float acc = 0.f;
#pragma unroll
            for (int j = 0; j < 4; ++j) {
                float2 x = __half22float2(ah[j]);
                float2 y = __half22float2(bh[j]);
                acc = fmaf(fmaxf(x.x - y.x, 0.f), wv[2 * j + 0], acc);
                acc = fmaf(fmaxf(x.y - y.y, 0.f), wv[2 * j + 1], acc);
            }
            acc += __shfl_xor(acc, 1);
            acc += __shfl_xor(acc, 2);
            acc += __shfl_xor(acc, 4);
            if (c == 0) out[eid[e]] = acc + b2[0];
        }
    }
}

extern "C" void kernel_launch(void* const* d_in, const int* in_sizes, int n_in,
                              void* d_out, int out_size, void* d_ws, size_t ws_size,
                              hipStream_t stream) {
    const float* K_h = (const float*)d_in[0];
    const float* Q_h = (const float*)d_in[1];
    const float* P_e = (const float*)d_in[2];
    const int*   src = (const int*)d_in[3];
    const int*   dst = (const int*)d_in[4];
    const float* W1  = (const float*)d_in[5];
    const float* b1  = (const float*)d_in[6];
    const float* W2  = (const float*)d_in[7];
    const float* b2  = (const float*)d_in[8];
    float* out = (float*)d_out;

    int n_nodes = in_sizes[0] / DD;
    int n_edges = in_sizes[3];

    int bdiv = (n_nodes + NB - 1) / NB;           // nodes per dst-bucket
    int cap  = ((n_edges / 4) + 3) & ~3;          // 2x mean bucket size, %4==0

    // Workspace layout (256B-aligned):
    //   A [n][64] fp16, B [n][64] fp16      (12.8 MB)
    //   sd  [NB*cap] int2 (binned src,dst)  (12.8 MB)
    //   eid [NB*cap] int  (original ids)    ( 6.4 MB)
    //   counts[NB]
    size_t nA = (size_t)n_nodes * DD;
    __half* A  = (__half*)d_ws;
    __half* Bm = A + nA;
    char* p = (char*)(Bm + nA);
    p = (char*)(((size_t)p + 255) & ~(size_t)255);
    int2* sd = (int2*)p;   p += (size_t)NB * cap * sizeof(int2);
    p = (char*)(((size_t)p + 255) & ~(size_t)255);
    int* eid = (int*)p;    p += (size_t)NB * cap * sizeof(int);
    p = (char*)(((size_t)p + 255) & ~(size_t)255);
    int* counts = (int*)p;

    node_transform_mfma<<<(n_nodes + NPB - 1) / NPB, 256, 0, stream>>>(
        K_h, Q_h, P_e, W1, b1, A, Bm, n_nodes, counts);
    bin_edges<<<256, 256, 0, stream>>>(src, dst, counts, sd, eid,
                                       n_edges, bdiv, cap,
                                       A, Bm, W2, b2, out);
    // 128 edges per block; blockIdx%8 = bucket (XCD-pinned B-slice)
    int blocks_per_bucket = (cap + 127) / 128;
    edge_score_binned<<<NB * blocks_per_bucket, 256, 0, stream>>>(
        A, Bm, sd, eid, counts, W2, b2, out, cap);
}

// Round 3
// 120.372 us; speedup vs baseline: 1.3533x; 1.1181x over previous
//
#include <hip/hip_runtime.h>
#include <hip/hip_fp16.h>

#define DD 64
#define NPB 64          // nodes per block (node kernel)
#define LP 72           // padded LDS row stride in halves (144 B): 2-way-only bank aliasing

typedef _Float16 f16x8 __attribute__((ext_vector_type(8)));
typedef float    f32x4 __attribute__((ext_vector_type(4)));
typedef int      i32x4 __attribute__((ext_vector_type(4)));
typedef float    fv4   __attribute__((ext_vector_type(4)));

// Node-level transform on MFMA f16 (fp32 accumulate):
//   A = (K_h + P_e) @ W1 + b1   (stored fp16)
//   B = Q_h @ W1                (stored fp16)
// 64 nodes/block, 4 waves; wave w computes rows w*16..w*16+15 of BOTH outputs
// via 16x16x32 MFMA (2 k-halves x 4 col-tiles x {A,B} = 16 mfma/wave).
__global__ __launch_bounds__(256) void node_transform_mfma(
    const float* __restrict__ K_h, const float* __restrict__ Q_h,
    const float* __restrict__ P_e, const float* __restrict__ W1,
    const float* __restrict__ b1, __half* __restrict__ A,
    __half* __restrict__ Bm, int n_nodes)
{
    __shared__ __half XH [NPB][LP];   // fp16(K+P)
    __shared__ __half QH [NPB][LP];   // fp16(Q)
    __shared__ __half W1T[DD][LP];    // W1 transposed: W1T[n][k] = W1[k][n]

    const int tid   = threadIdx.x;
    const int nbase = blockIdx.x * NPB;

    // ---- Stage W1T (8 KB): thread t reads W1[k][n0..n0+15], scatters column-wise ----
    {
        const int k  = tid >> 2;
        const int n0 = (tid & 3) << 4;
        const float* wr = W1 + k * DD + n0;
        float4 w0 = *(const float4*)(wr);
        float4 w1v = *(const float4*)(wr + 4);
        float4 w2v = *(const float4*)(wr + 8);
        float4 w3v = *(const float4*)(wr + 12);
        const float wv[16] = {w0.x,w0.y,w0.z,w0.w, w1v.x,w1v.y,w1v.z,w1v.w,
                              w2v.x,w2v.y,w2v.z,w2v.w, w3v.x,w3v.y,w3v.z,w3v.w};
#pragma unroll
        for (int j = 0; j < 16; ++j)
            W1T[n0 + j][k] = __float2half(wv[j]);
    }

    // ---- Stage XH = fp16(K+P), QH = fp16(Q); coalesced float4 global reads ----
#pragma unroll
    for (int ch = 0; ch < 4; ++ch) {
        int idx = tid + (ch << 8);        // float4 index over [64 rows][16]
        int r   = idx >> 4;
        int q4  = idx & 15;
        int node = nbase + r;
        float4 kv = make_float4(0.f,0.f,0.f,0.f);
        float4 pv = kv, qv = kv;
        if (node < n_nodes) {
            kv = *(const float4*)(K_h + (size_t)node * DD + q4 * 4);
            pv = *(const float4*)(P_e + (size_t)node * DD + q4 * 4);
            qv = *(const float4*)(Q_h + (size_t)node * DD + q4 * 4);
        }
        __half2* xh = (__half2*)&XH[r][q4 << 2];
        xh[0] = __float22half2_rn(make_float2(kv.x + pv.x, kv.y + pv.y));
        xh[1] = __float22half2_rn(make_float2(kv.z + pv.z, kv.w + pv.w));
        __half2* qh = (__half2*)&QH[r][q4 << 2];
        qh[0] = __float22half2_rn(make_float2(qv.x, qv.y));
        qh[1] = __float22half2_rn(make_float2(qv.z, qv.w));
    }
    __syncthreads();

    // ---- MFMA main: wave w, lane (m = lane&15, q = lane>>4) ----
    const int w    = tid >> 6;
    const int lane = tid & 63;
    const int m    = lane & 15;
    const int q    = lane >> 4;
    const int row  = (w << 4) + m;

    f16x8 xlo = *(const f16x8*)&XH[row][(q << 3)];
    f16x8 xhi = *(const f16x8*)&XH[row][32 + (q << 3)];
    f16x8 qlo = *(const f16x8*)&QH[row][(q << 3)];
    f16x8 qhi = *(const f16x8*)&QH[row][32 + (q << 3)];

    f32x4 accA[4], accB[4];
#pragma unroll
    for (int t = 0; t < 4; ++t) {
        float bb = b1[t * 16 + m];            // b1 folded into A accumulator
        accA[t] = (f32x4){bb, bb, bb, bb};
        accB[t] = (f32x4){0.f, 0.f, 0.f, 0.f};
        f16x8 wlo = *(const f16x8*)&W1T[t * 16 + m][(q << 3)];
        f16x8 whi = *(const f16x8*)&W1T[t * 16 + m][32 + (q << 3)];
        accA[t] = __builtin_amdgcn_mfma_f32_16x16x32_f16(xlo, wlo, accA[t], 0, 0, 0);
        accA[t] = __builtin_amdgcn_mfma_f32_16x16x32_f16(xhi, whi, accA[t], 0, 0, 0);
        accB[t] = __builtin_amdgcn_mfma_f32_16x16x32_f16(qlo, wlo, accB[t], 0, 0, 0);
        accB[t] = __builtin_amdgcn_mfma_f32_16x16x32_f16(qhi, whi, accB[t], 0, 0, 0);
    }

    // ---- Store: acc[t][r] -> out[nbase + w*16 + q*4 + r][t*16 + m] ----
#pragma unroll
    for (int r = 0; r < 4; ++r) {
        int node = nbase + (w << 4) + (q << 2) + r;
        if (node >= n_nodes) continue;
        __half* Arow = A  + (size_t)node * DD + m;
        __half* Brow = Bm + (size_t)node * DD + m;
#pragma unroll
        for (int t = 0; t < 4; ++t) {
            Arow[t * 16] = __float2half(accA[t][r]);
            Brow[t * 16] = __float2half(accB[t][r]);
        }
    }
}

// Edge-level: score[e] = relu(A[src[e]] - B[dst[e]]) . W2 + b2
// 8 lanes per edge, 4 edges (one quad) per lane-group — the R0 structure,
// made persistent: 2048 blocks grid-stride over quads, with the NEXT quad's
// src/dst indices prefetched so the index-load latency hides under the
// current quad's row gathers. src/dst/out are nontemporal (zero-reuse
// streams; keep them out of L2 so A/B rows keep their ~31% hit rate).
__global__ __launch_bounds__(256) void edge_score_kernel(
    const __half* __restrict__ A, const __half* __restrict__ Bm,
    const int* __restrict__ src, const int* __restrict__ dst,
    const float* __restrict__ W2, const float* __restrict__ b2,
    float* __restrict__ out, int n_edges)
{
    const int tid = threadIdx.x;
    const int g   = tid >> 3;                   // lane-group 0..31
    const int c   = tid & 7;                    // 16B chunk within row
    const int nq  = n_edges >> 2;               // full quads
    const int tg  = gridDim.x << 5;             // total lane-groups in grid

    float4 w0 = *(const float4*)(W2 + c * 8);   // uniform -> s_load
    float4 w1 = *(const float4*)(W2 + c * 8 + 4);
    const float wv[8] = {w0.x, w0.y, w0.z, w0.w, w1.x, w1.y, w1.z, w1.w};
    const size_t coff = (size_t)(c * 8);
    const float bb = b2[0];

    int q = (blockIdx.x << 5) + g;
    if (q < nq) {
        i32x4 sv = __builtin_nontemporal_load((const i32x4*)(src + (q << 2)));
        i32x4 dv = __builtin_nontemporal_load((const i32x4*)(dst + (q << 2)));
        for (;;) {
            const int e0 = q << 2;
            const int qn = q + tg;
            const bool more = (qn < nq);
            i32x4 svn, dvn;
            if (more) {   // prefetch next quad's indices
                svn = __builtin_nontemporal_load((const i32x4*)(src + (qn << 2)));
                dvn = __builtin_nontemporal_load((const i32x4*)(dst + (qn << 2)));
            }

            // Issue all 8 row loads back-to-back.
            float4 ra0 = *(const float4*)(A  + (size_t)sv[0] * DD + coff);
            float4 rb0 = *(const float4*)(Bm + (size_t)dv[0] * DD + coff);
            float4 ra1 = *(const float4*)(A  + (size_t)sv[1] * DD + coff);
            float4 rb1 = *(const float4*)(Bm + (size_t)dv[1] * DD + coff);
            float4 ra2 = *(const float4*)(A  + (size_t)sv[2] * DD + coff);
            float4 rb2 = *(const float4*)(Bm + (size_t)dv[2] * DD + coff);
            float4 ra3 = *(const float4*)(A  + (size_t)sv[3] * DD + coff);
            float4 rb3 = *(const float4*)(Bm + (size_t)dv[3] * DD + coff);

            float acc0 = 0.f, acc1 = 0.f, acc2 = 0.f, acc3 = 0.f;
            const __half2* ah0 = (const __half2*)&ra0;
            const __half2* bh0 = (const __half2*)&rb0;
            const __half2* ah1 = (const __half2*)&ra1;
            const __half2* bh1 = (const __half2*)&rb1;
            const __half2* ah2 = (const __half2*)&ra2;
            const __half2* bh2 = (const __half2*)&rb2;
            const __half2* ah3 = (const __half2*)&ra3;
            const __half2* bh3 = (const __half2*)&rb3;
#pragma unroll
            for (int j = 0; j < 4; ++j) {
                float2 x, y;
                x = __half22float2(ah0[j]); y = __half22float2(bh0[j]);
                acc0 = fmaf(fmaxf(x.x - y.x, 0.f), wv[2 * j + 0], acc0);
                acc0 = fmaf(fmaxf(x.y - y.y, 0.f), wv[2 * j + 1], acc0);
                x = __half22float2(ah1[j]); y = __half22float2(bh1[j]);
                acc1 = fmaf(fmaxf(x.x - y.x, 0.f), wv[2 * j + 0], acc1);
                acc1 = fmaf(fmaxf(x.y - y.y, 0.f), wv[2 * j + 1], acc1);
                x = __half22float2(ah2[j]); y = __half22float2(bh2[j]);
                acc2 = fmaf(fmaxf(x.x - y.x, 0.f), wv[2 * j + 0], acc2);
                acc2 = fmaf(fmaxf(x.y - y.y, 0.f), wv[2 * j + 1], acc2);
                x = __half22float2(ah3[j]); y = __half22float2(bh3[j]);
                acc3 = fmaf(fmaxf(x.x - y.x, 0.f), wv[2 * j + 0], acc3);
                acc3 = fmaf(fmaxf(x.y - y.y, 0.f), wv[2 * j + 1], acc3);
            }

            acc0 += __shfl_xor(acc0, 1); acc1 += __shfl_xor(acc1, 1);
            acc2 += __shfl_xor(acc2, 1); acc3 += __shfl_xor(acc3, 1);
            acc0 += __shfl_xor(acc0, 2); acc1 += __shfl_xor(acc1, 2);
            acc2 += __shfl_xor(acc2, 2); acc3 += __shfl_xor(acc3, 2);
            acc0 += __shfl_xor(acc0, 4); acc1 += __shfl_xor(acc1, 4);
            acc2 += __shfl_xor(acc2, 4); acc3 += __shfl_xor(acc3, 4);

            if (c == 0) {
                fv4 r;
                r[0] = acc0 + bb; r[1] = acc1 + bb;
                r[2] = acc2 + bb; r[3] = acc3 + bb;
                __builtin_nontemporal_store(r, (fv4*)(out + e0));
            }

            if (!more) break;
            q = qn; sv = svn; dv = dvn;
        }
    }

    // Remainder edges (n_edges % 4): block 0, lane-group 0 only.
    const int rem = n_edges & 3;
    if (rem && blockIdx.x == 0 && g == 0) {
        for (int e = n_edges - rem; e < n_edges; ++e) {
            int s = src[e], d = dst[e];
            float4 ar = *(const float4*)(A  + (size_t)s * DD + coff);
            float4 br = *(const float4*)(Bm + (size_t)d * DD + coff);
            const __half2* ah = (const __half2*)&ar;
            const __half2* bh = (const __half2*)&br;
            float acc = 0.f;
#pragma unroll
            for (int j = 0; j < 4; ++j) {
                float2 x = __half22float2(ah[j]);
                float2 y = __half22float2(bh[j]);
                acc = fmaf(fmaxf(x.x - y.x, 0.f), wv[2 * j + 0], acc);
                acc = fmaf(fmaxf(x.y - y.y, 0.f), wv[2 * j + 1], acc);
            }
            acc += __shfl_xor(acc, 1);
            acc += __shfl_xor(acc, 2);
            acc += __shfl_xor(acc, 4);
            if (c == 0) out[e] = acc + bb;
        }
    }
}

extern "C" void kernel_launch(void* const* d_in, const int* in_sizes, int n_in,
                              void* d_out, int out_size, void* d_ws, size_t ws_size,
                              hipStream_t stream) {
    const float* K_h = (const float*)d_in[0];
    const float* Q_h = (const float*)d_in[1];
    const float* P_e = (const float*)d_in[2];
    const int*   src = (const int*)d_in[3];
    const int*   dst = (const int*)d_in[4];
    const float* W1  = (const float*)d_in[5];
    const float* b1  = (const float*)d_in[6];
    const float* W2  = (const float*)d_in[7];
    const float* b2  = (const float*)d_in[8];
    float* out = (float*)d_out;

    int n_nodes = in_sizes[0] / DD;
    int n_edges = in_sizes[3];

    // Workspace: A [n][64] fp16, B [n][64] fp16 (12.8 MB total)
    __half* A  = (__half*)d_ws;
    __half* Bm = A + (size_t)n_nodes * DD;

    node_transform_mfma<<<(n_nodes + NPB - 1) / NPB, 256, 0, stream>>>(
        K_h, Q_h, P_e, W1, b1, A, Bm, n_nodes);

    // Persistent grid: 2048 blocks (8 blocks/CU target), 32 lane-groups each,
    // grid-stride over edge-quads with index prefetch.
    int nq = n_edges >> 2;
    int grid = (nq + 31) >> 5;
    if (grid > 2048) grid = 2048;
    if (grid < 1) grid = 1;
    edge_score_kernel<<<grid, 256, 0, stream>>>(
        A, Bm, src, dst, W2, b2, out, n_edges);
}